// Round 17
// baseline (3328.960 us; speedup 1.0000x reference)
//
#include <hip/hip_runtime.h>

#define TSTEPS 20
constexpr float THRES = 1.0f;
constexpr float DECAY = 0.875f;  // (2^3-1)/2^3

constexpr int DIM_IN = 64;
constexpr int NIN = DIM_IN * DIM_IN;          // 4096
constexpr int C1 = 64, K1 = 7, D1 = 58;
constexpr int N1 = C1 * D1 * D1;              // 215296
constexpr int C2 = 128, K2 = 7, D2 = 52;
constexpr int N2 = C2 * D2 * D2;              // 346112
constexpr int NFLAT = N2;
constexpr int NHID = 512;
constexpr int NOUT = 10;
constexpr int KC = 16;          // conv2 K-split chunks (chunk size unchanged)
constexpr int CPC = C1 / KC;    // 4 input channels per chunk
constexpr int W2R_ELEMS = 256 * 28 * 64;      // reshuffled conv2 weights (8-co groups)

// ---- step-dispatch D_k roles ----
// Round-17: partial deepened 4x (208 blocks, each does 4 kc chunks
// sequentially). Partial now holds only ~208/1024 resident slots for its
// ~21 us VALU phase -> gather/reduce/conv1 run fully concurrent under it.
constexpr int R_PART = 208;                    // (yt, cotg, kcg)
constexpr int R_GATH = 384;
constexpr int R_RED = N2 / 256;                // 1352
constexpr int B_C1S = R_PART;                  // 208
constexpr int B_FIN0 = B_C1S + C1;             // 272
constexpr int B_INPUT = B_FIN0 + 8;            // 280
constexpr int B_LIN2 = B_INPUT + 1;            // 281
constexpr int B_MISC = B_LIN2 + 1;             // 282
constexpr int B_GATH0 = B_MISC + 1;            // 283
constexpr int B_RED0 = B_GATH0 + R_GATH;       // 667
constexpr int NBS = B_RED0 + R_RED;            // 2019
// appended one-time roles (k<=3): transpose strips, then reshuffle (k==1)
constexpr int NT = 1803;                       // strips per early dispatch
constexpr int B_TR0 = NBS;                     // 2019
constexpr int B_RSH0 = NBS + NT;               // 3822
constexpr int NBS_T = B_RSH0 + 64;             // 3886

// Persistent state (re-initialized every kernel_launch).
__device__ float g_mp_in[NIN];
__device__ float g_s_in[2][NIN];       // slot s&1: input-spikes of step s
__device__ float g_mp_c1[N1];
__device__ float g_sp_c1[2][N1];       // slot s&1: conv1 spikes of step s
__device__ float g_mp_c2[N2];
__device__ float g_sp_c2[N2];          // dense fallback path only
__device__ float g_mp_l1[NHID];
__device__ float g_sp_l1[2][NHID];     // slot s&1: linear1 spikes of step s
__device__ float g_mp_l2[NOUT];
__device__ float g_dot[2][NHID];       // dense-fallback dot, slot s&1
__device__ double g_dotp[2][R_GATH][NHID];  // gather partials (fp64, 3.1 MB)
__device__ int   g_nnz[4];             // slot s&3: conv2 spike count of step s
__device__ int   g_list[4][N2];        // slot s&3: spike indices
__device__ float g_part[2][KC * N2];   // slot s&1: conv2 K-split partials
__device__ float g_w2r[W2R_ELEMS];     // reshuffled conv2 weights

// init: zero state; fold input(0) and input(1) (image-only, deterministic):
// t=0: mp=image<1 -> no fire; t=1: mp=2*image, fire -> s_in slot 1.
__global__ void init_kernel(const float* __restrict__ image, float* __restrict__ out) {
    int i = blockIdx.x * blockDim.x + threadIdx.x;
    int stride = gridDim.x * blockDim.x;
    for (int j = i; j < NIN; j += stride) {
        float mp = 2.f * image[j];
        float f = (mp >= THRES) ? 1.f : 0.f;
        g_mp_in[j] = mp - THRES * f;
        g_s_in[1][j] = f;              // s_in(1), read by conv1(1) in D_1
        g_s_in[0][j] = 0.f;
    }
    for (int j = i; j < N1; j += stride) {
        g_mp_c1[j] = 0.f; g_sp_c1[0][j] = 0.f; g_sp_c1[1][j] = 0.f;
    }
    for (int j = i; j < N2; j += stride) { g_mp_c2[j] = 0.f; g_sp_c2[j] = 0.f; }
    if (i < NHID) {
        g_mp_l1[i] = 0.f; g_sp_l1[0][i] = 0.f; g_sp_l1[1][i] = 0.f;
        g_dot[0][i] = 0.f; g_dot[1][i] = 0.f;
    }
    if (i < NOUT) g_mp_l2[i] = 0.f;
    if (i < (TSTEPS + 1) * NOUT) out[i] = 0.f;
    if (i < 4) g_nnz[i] = 0;
}

// ---- the one dispatch per pipeline slot k (k = 1..21) ----
// D_k = partial(k)|conv1(k)|finish(k-2)|input(k+1)|linear2(k-2)|misc
//       |gather(k-1)|reduce(k-1) [+ transpose strips k<=3, reshuffle k=1].
__global__ void __launch_bounds__(256, 4) step_kernel(const float* __restrict__ w1,
                                                      const float* __restrict__ w2full,
                                                      const float* __restrict__ wl1,
                                                      const float* __restrict__ wT,
                                                      const float* __restrict__ wl2,
                                                      const float* __restrict__ image,
                                                      float* __restrict__ out,
                                                      int k, int sparse) {
    __shared__ union __align__(16) {
        float spk[CPC][10][58];           // 9.28 KB (partial)
        float sim[NIN];                   // 16 KB  (conv1)
        double fin[256];                  // 2 KB   (finish)
        struct { int wcnt[4]; int base; } red;  // (reduce list-build)
        float tile[64][65];               // 16.64 KB (transpose strip)
    } sm;
    int nb = blockIdx.x, tid = threadIdx.x;
    int wid = tid >> 6, lane = tid & 63;

    if (nb < R_PART) {
        // ---- conv2 partial, step s=k in [2,17]: reads sp_c1(k-1) ----
        // 4 kc chunks per block, sequentially; chunk internals identical to
        // the proven r13/r16 form (CPC=4, v[4][7], scalar weights).
        if (k < 2 || k > 17) return;
        int kcg = nb & 3;
        int tmp = nb >> 2;             // 0..51
        int cotg = tmp & 3;
        int yt = tmp >> 2;             // 0..12
        int y0 = yt * 4;
        const float* __restrict__ sp = g_sp_c1[(k + 1) & 1];
        int cot = __builtin_amdgcn_readfirstlane(cotg * 4 + wid);
        int co0 = cot * 8;
        bool act = lane < D2;
        float* __restrict__ pb = g_part[k & 1];
#pragma unroll 1
        for (int kcq = 0; kcq < 4; ++kcq) {
            int kc = kcg * 4 + kcq;
            int c0 = kc * CPC;
            __syncthreads();           // prev compute done before restage
            for (int e = tid; e < CPC * 10 * 58; e += 256) {
                int c = e / 580, rem = e - c * 580;
                int r = rem / 58, x = rem - r * 58;
                sm.spk[c][r][x] = sp[(c0 + c) * (D1 * D1) + (y0 + r) * D1 + x];
            }
            __syncthreads();
            float acc[8][4] = {};
#pragma unroll 1
            for (int c = 0; c < CPC; ++c) {
#pragma unroll
                for (int ky = 0; ky < K2; ++ky) {
                    // hoist spike regs out of the cl loop
                    float v[4][7];
                    if (act) {
#pragma unroll
                        for (int o = 0; o < 4; ++o)
#pragma unroll
                            for (int kx = 0; kx < 7; ++kx)
                                v[o][kx] = sm.spk[c][o + ky][lane + kx];
                    }
                    const float* __restrict__ wrow =
                        g_w2r + ((size_t)(kc * 16 + cot) * 28 + (c * 7 + ky)) * 64;
#pragma unroll
                    for (int cl = 0; cl < 8; ++cl) {
                        float wv[7];   // 7 live scalar weights at a time
#pragma unroll
                        for (int kx = 0; kx < 7; ++kx) wv[kx] = wrow[cl * 8 + kx];
                        if (act) {
#pragma unroll
                            for (int o = 0; o < 4; ++o)
#pragma unroll
                                for (int kx = 0; kx < 7; ++kx)
                                    acc[cl][o] = fmaf(v[o][kx], wv[kx], acc[cl][o]);
                        }
                    }
                }
            }
            if (act) {
#pragma unroll
                for (int cl = 0; cl < 8; ++cl)
#pragma unroll
                    for (int o = 0; o < 4; ++o)
                        pb[(size_t)kc * N2 + (co0 + cl) * (D2 * D2) +
                           (y0 + o) * D2 + lane] = acc[cl][o];
            }
        }
    } else if (nb < B_FIN0) {
        // ---- conv1, step s=k in [1,16]: reads s_in(k) ----
        if (k < 1 || k > 16) return;
        int co = nb - B_C1S;
        const float4* __restrict__ s4 = (const float4*)g_s_in[k & 1];
        float4* d4 = (float4*)sm.sim;
        for (int j = tid; j < NIN / 4; j += 256) d4[j] = s4[j];
        __syncthreads();
        float w[49];
#pragma unroll
        for (int kk = 0; kk < 49; ++kk) w[kk] = w1[co * 49 + kk];
        float* __restrict__ spb = g_sp_c1[k & 1];
        for (int idx = tid; idx < D1 * D1; idx += 256) {
            int y = idx / D1, x = idx - y * D1;
            float a = 0.f;
#pragma unroll
            for (int ky = 0; ky < K1; ++ky)
#pragma unroll
                for (int kx = 0; kx < K1; ++kx)
                    a = fmaf(sm.sim[(y + ky) * DIM_IN + x + kx], w[ky * K1 + kx], a);
            int o = co * (D1 * D1) + idx;
            float mp = g_mp_c1[o] + a;
            float f = (mp >= THRES) ? 1.f : 0.f;
            g_mp_c1[o] = (mp - THRES * f) * ((f > 0.f) ? 1.f : DECAY);
            spb[o] = f;
        }
    } else if (nb < B_INPUT) {
        // ---- linear1 finish, step s=k-2 in [3,18]: reads dotp(s) ----
        if (k < 5 || k > 20) return;
        int s = k - 2;
        int fb = nb - B_FIN0;              // 0..7
        int hl = tid & 63, wch = tid >> 6;
        int h = fb * 64 + hl;
        float tot;
        if (sparse) {
            int p = s & 1;
            double sum = 0.0;
            int b0 = wch * (R_GATH / 4);   // 96 blocks per chunk
            for (int b = b0; b < b0 + R_GATH / 4; ++b) sum += g_dotp[p][b][h];
            sm.fin[wch * 64 + hl] = sum;
            __syncthreads();
            if (wch != 0) return;
            tot = (float)((sm.fin[hl] + sm.fin[64 + hl]) +
                          (sm.fin[128 + hl] + sm.fin[192 + hl]));
        } else {
            if (wch != 0) return;
            tot = g_dot[s & 1][h];
        }
        float mp = g_mp_l1[h] * DECAY + tot;
        float f = (mp >= THRES) ? 1.f : 0.f;
        g_mp_l1[h] = mp - THRES * f;
        g_sp_l1[s & 1][h] = f;
    } else if (nb == B_INPUT) {
        // ---- input integrate/fire, step s=k+1 in [2,16] ----
        if (k < 1 || k > 15) return;
        int s = k + 1;
        float* __restrict__ sb = g_s_in[s & 1];
        for (int j = tid; j < NIN; j += 256) {
            float mp = g_mp_in[j] + image[j];
            float f = (mp >= THRES) ? 1.f : 0.f;
            sb[j] = f;
            g_mp_in[j] = mp - THRES * f;   // SnnInput: no decay
        }
    } else if (nb == B_LIN2) {
        // ---- linear2, step s=k-2 in [4,19]: reads sp_l1(s-1) ----
        if (k < 6 || k > 21) return;
        int s = k - 2;
        const float* __restrict__ sl = g_sp_l1[(s - 1) & 1];
        for (int o = wid; o < NOUT; o += 4) {
            float a = 0.f;
#pragma unroll
            for (int kk = lane; kk < NHID; kk += 64)
                a = fmaf(wl2[o * NHID + kk], sl[kk], a);
            for (int off = 32; off; off >>= 1) a += __shfl_down(a, off, 64);
            if (lane == 0) {
                float mp = g_mp_l2[o] * DECAY + a;
                float f = (mp >= THRES) ? 1.f : 0.f;
                g_mp_l2[o] = mp - THRES * f;
                out[(s + 1) * NOUT + o] = f;
            }
        }
    } else if (nb == B_MISC) {
        // ---- misc: zero nnz[k&3] for reduce(k) (runs in D_{k+1}) ----
        if (k < 2 || k > 17) return;
        if (tid == 0) g_nnz[k & 3] = 0;
    } else if (nb < B_RED0) {
        // ---- linear1 gather, step s=k-1 in [3,18]: reads list(s-1) ----
        if (!sparse || k < 4 || k > 19) return;
        int s = k - 1;
        int gb = nb - B_GATH0;
        int ps = (s - 1) & 3;
        int nnz = g_nnz[ps];
        const int* __restrict__ list = g_list[ps];
        const float2* __restrict__ wT2 = (const float2*)wT;
        int h = tid;
        double ax[8] = {}, ay[8] = {};
        int i = gb;
        for (; i + 7 * R_GATH < nnz; i += 8 * R_GATH) {
            int j[8];
#pragma unroll
            for (int u = 0; u < 8; ++u) j[u] = list[i + u * R_GATH];
#pragma unroll
            for (int u = 0; u < 8; ++u) {
                float2 w = wT2[(size_t)j[u] * 256 + h];
                ax[u] += w.x; ay[u] += w.y;
            }
        }
        for (; i < nnz; i += R_GATH) {
            float2 w = wT2[(size_t)list[i] * 256 + h];
            ax[0] += w.x; ay[0] += w.y;
        }
        g_dotp[s & 1][gb][2 * h] =
            ((ax[0] + ax[1]) + (ax[2] + ax[3])) + ((ax[4] + ax[5]) + (ax[6] + ax[7]));
        g_dotp[s & 1][gb][2 * h + 1] =
            ((ay[0] + ay[1]) + (ay[2] + ay[3])) + ((ay[4] + ay[5]) + (ay[6] + ay[7]));
    } else if (nb < NBS) {
        // ---- conv2 reduce, step s=k-1 in [2,17]: block-aggregated list ----
        if (k < 3 || k > 18) return;
        int s = k - 1;
        int i = (nb - B_RED0) * 256 + tid;
        const float* __restrict__ pb = g_part[s & 1];
        float sum = 0.f;
#pragma unroll
        for (int kk = 0; kk < KC; ++kk) sum += pb[(size_t)kk * N2 + i];
        float mp = g_mp_c2[i] + sum;
        float f = (mp >= THRES) ? 1.f : 0.f;
        g_mp_c2[i] = (mp - THRES * f) * ((f > 0.f) ? 1.f : DECAY);
        if (!sparse) g_sp_c2[i] = f;
        bool spike = f > 0.f;
        unsigned long long m = __ballot(spike);
        int lpre = __popcll(m & ((1ull << lane) - 1));
        if (lane == 0) sm.red.wcnt[wid] = __popcll(m);
        __syncthreads();
        int w0 = sm.red.wcnt[0], w1c = sm.red.wcnt[1],
            w2c = sm.red.wcnt[2], w3c = sm.red.wcnt[3];
        int total = w0 + w1c + w2c + w3c;
        if (tid == 0 && total > 0)
            sm.red.base = atomicAdd(&g_nnz[s & 3], total);
        __syncthreads();
        if (spike) {
            int woff = (wid > 0 ? w0 : 0) + (wid > 1 ? w1c : 0) + (wid > 2 ? w2c : 0);
            g_list[s & 3][sm.red.base + woff + lpre] = i;
        }
    } else if (nb < B_RSH0) {
        // ---- transpose strip (k<=3, appended): w_l1 -> wT, 64-col strip ----
        if (!sparse || k > 3) return;
        int sg = (nb - B_TR0) + (k - 1) * NT;
        if (sg >= NFLAT / 64) return;
        int bx = sg * 64;
        int tx = tid & 63, ty = tid >> 6;
        float* __restrict__ wTm = (float*)wT;
#pragma unroll 1
        for (int rt = 0; rt < NHID / 64; ++rt) {
            int by = rt * 64;
#pragma unroll
            for (int kk = 0; kk < 16; ++kk)
                sm.tile[ty + 4 * kk][tx] =
                    wl1[(size_t)(by + ty + 4 * kk) * NFLAT + bx + tx];
            __syncthreads();
#pragma unroll
            for (int kk = 0; kk < 16; ++kk)
                wTm[(size_t)(bx + ty + 4 * kk) * NHID + by + tx] =
                    sm.tile[tx][ty + 4 * kk];
            __syncthreads();
        }
    } else {
        // ---- reshuffle w_c2 -> g_w2r (k==1 only, appended, 64 blocks) ----
        // layout: [(kc*16+cot8)][c*7+ky][cl*8+kx], cl in [0,8), kx pad 8
        if (k != 1) return;
        int rb = nb - B_RSH0;              // 0..63
        for (int idx = rb * 256 + tid; idx < C2 * C1 * 49; idx += 64 * 256) {
            int co = idx / (C1 * 49);
            int rem = idx - co * (C1 * 49);
            int ci = rem / 49;
            int kk2 = rem - ci * 49;
            int ky = kk2 / 7, kx = kk2 - ky * 7;
            int kc = ci >> 2, c = ci & 3;
            int cot = co >> 3, cl = co & 7;
            g_w2r[((size_t)(kc * 16 + cot) * 28 + (c * 7 + ky)) * 64 + cl * 8 + kx] =
                w2full[idx];
        }
    }
}

// Dense fallback (ws too small for wT): writes g_dot[slot]; finish applies it.
__global__ void __launch_bounds__(256) linear1_dense(const float* __restrict__ wl1,
                                                     int slot) {
    int row = blockIdx.x;
    const float4* __restrict__ w4 = (const float4*)(wl1 + (size_t)row * NFLAT);
    const float4* __restrict__ s4 = (const float4*)g_sp_c2;
    float acc = 0.f;
    for (int j = threadIdx.x; j < NFLAT / 4; j += 256) {
        float4 w = w4[j];
        float4 s = s4[j];
        acc += w.x * s.x + w.y * s.y + w.z * s.z + w.w * s.w;
    }
    __shared__ float red[256];
    red[threadIdx.x] = acc;
    __syncthreads();
    for (int off = 128; off >= 1; off >>= 1) {
        if (threadIdx.x < off) red[threadIdx.x] += red[threadIdx.x + off];
        __syncthreads();
    }
    if (threadIdx.x == 0) g_dot[slot][row] = red[0];
}

extern "C" void kernel_launch(void* const* d_in, const int* in_sizes, int n_in,
                              void* d_out, int out_size, void* d_ws, size_t ws_size,
                              hipStream_t stream) {
    const float* image = (const float*)d_in[0];
    const float* w_c1 = (const float*)d_in[1];
    const float* w_c2 = (const float*)d_in[2];
    const float* w_l1 = (const float*)d_in[3];
    const float* w_l2 = (const float*)d_in[4];
    float* out = (float*)d_out;

    float* wT = (float*)d_ws;
    bool sparse = ws_size >= (size_t)NFLAT * NHID * sizeof(float);

    init_kernel<<<512, 256, 0, stream>>>(image, out);

    // Pipeline: D_k = partial(k)|conv1(k)|finish(k-2)|input(k+1)|linear2(k-2)
    //                 |misc|gather(k-1)|reduce(k-1) [+transpose k<=3].
    for (int k = 1; k <= 21; ++k) {
        int grid = (k <= 3) ? NBS_T : NBS;
        step_kernel<<<grid, 256, 0, stream>>>(w_c1, w_c2, w_l1, wT, w_l2, image,
                                              out, k, sparse ? 1 : 0);
        if (!sparse && k >= 3 && k <= 18)
            linear1_dense<<<NHID, 256, 0, stream>>>(w_l1, k & 1);
    }
}

// Round 18
// 1614.590 us; speedup vs baseline: 2.0618x; 2.0618x over previous
//
#include <hip/hip_runtime.h>

#define TSTEPS 20
constexpr float THRES = 1.0f;
constexpr float DECAY = 0.875f;  // (2^3-1)/2^3

constexpr int DIM_IN = 64;
constexpr int NIN = DIM_IN * DIM_IN;          // 4096
constexpr int C1 = 64, K1 = 7, D1 = 58;
constexpr int N1 = C1 * D1 * D1;              // 215296
constexpr int C2 = 128, K2 = 7, D2 = 52;
constexpr int N2 = C2 * D2 * D2;              // 346112
constexpr int NFLAT = N2;
constexpr int NHID = 512;
constexpr int NOUT = 10;
constexpr int KC = 16;          // conv2 K-split chunks (16/CPC=4 proven best)
constexpr int CPC = C1 / KC;    // 4 input channels per chunk
constexpr int W2R_ELEMS = 256 * 28 * 64;      // reshuffled conv2 weights (8-co groups)

// ---- step-dispatch D_k roles (round-16 layout — proven best, 1615 us) ----
// Order: [partial | conv1 | finish | input | lin2 | misc | gather | reduce].
// partial at 832 blocks = 3.25 blocks/CU = ~3 waves/SIMD: enough intra-role
// TLP to hide scalar-weight-load + staging latency (r17's 208-block depth-4
// variant exposed those latencies and regressed 2x). gather at 384 deeper
// blocks partially overlaps partial's VALU phase (r16: -35 us vs r15).
constexpr int R_PART = 832;                    // (kc, yt, cotg)
constexpr int R_GATH = 384;
constexpr int R_RED = N2 / 256;                // 1352
constexpr int B_C1S = R_PART;                  // 832
constexpr int B_FIN0 = B_C1S + C1;             // 896
constexpr int B_INPUT = B_FIN0 + 8;            // 904
constexpr int B_LIN2 = B_INPUT + 1;            // 905
constexpr int B_MISC = B_LIN2 + 1;             // 906
constexpr int B_GATH0 = B_MISC + 1;            // 907
constexpr int B_RED0 = B_GATH0 + R_GATH;       // 1291
constexpr int NBS = B_RED0 + R_RED;            // 2643
// appended one-time roles (k<=3): transpose strips, then reshuffle (k==1)
constexpr int NT = 1803;                       // strips per early dispatch
constexpr int B_TR0 = NBS;                     // 2643
constexpr int B_RSH0 = NBS + NT;               // 4446
constexpr int NBS_T = B_RSH0 + 64;             // 4510

// Persistent state (re-initialized every kernel_launch).
__device__ float g_mp_in[NIN];
__device__ float g_s_in[2][NIN];       // slot s&1: input-spikes of step s
__device__ float g_mp_c1[N1];
__device__ float g_sp_c1[2][N1];       // slot s&1: conv1 spikes of step s
__device__ float g_mp_c2[N2];
__device__ float g_sp_c2[N2];          // dense fallback path only
__device__ float g_mp_l1[NHID];
__device__ float g_sp_l1[2][NHID];     // slot s&1: linear1 spikes of step s
__device__ float g_mp_l2[NOUT];
__device__ float g_dot[2][NHID];       // dense-fallback dot, slot s&1
__device__ double g_dotp[2][R_GATH][NHID];  // gather partials (fp64, 3.1 MB)
__device__ int   g_nnz[4];             // slot s&3: conv2 spike count of step s
__device__ int   g_list[4][N2];        // slot s&3: spike indices
__device__ float g_part[2][KC * N2];   // slot s&1: conv2 K-split partials
__device__ float g_w2r[W2R_ELEMS];     // reshuffled conv2 weights

// init: zero state; fold input(0) and input(1) (image-only, deterministic):
// t=0: mp=image<1 -> no fire; t=1: mp=2*image, fire -> s_in slot 1.
__global__ void init_kernel(const float* __restrict__ image, float* __restrict__ out) {
    int i = blockIdx.x * blockDim.x + threadIdx.x;
    int stride = gridDim.x * blockDim.x;
    for (int j = i; j < NIN; j += stride) {
        float mp = 2.f * image[j];
        float f = (mp >= THRES) ? 1.f : 0.f;
        g_mp_in[j] = mp - THRES * f;
        g_s_in[1][j] = f;              // s_in(1), read by conv1(1) in D_1
        g_s_in[0][j] = 0.f;
    }
    for (int j = i; j < N1; j += stride) {
        g_mp_c1[j] = 0.f; g_sp_c1[0][j] = 0.f; g_sp_c1[1][j] = 0.f;
    }
    for (int j = i; j < N2; j += stride) { g_mp_c2[j] = 0.f; g_sp_c2[j] = 0.f; }
    if (i < NHID) {
        g_mp_l1[i] = 0.f; g_sp_l1[0][i] = 0.f; g_sp_l1[1][i] = 0.f;
        g_dot[0][i] = 0.f; g_dot[1][i] = 0.f;
    }
    if (i < NOUT) g_mp_l2[i] = 0.f;
    if (i < (TSTEPS + 1) * NOUT) out[i] = 0.f;
    if (i < 4) g_nnz[i] = 0;
}

// ---- the one dispatch per pipeline slot k (k = 1..21) ----
// D_k = partial(k)|conv1(k)|finish(k-2)|input(k+1)|linear2(k-2)|misc
//       |gather(k-1)|reduce(k-1) [+ transpose strips k<=3, reshuffle k=1].
__global__ void __launch_bounds__(256, 4) step_kernel(const float* __restrict__ w1,
                                                      const float* __restrict__ w2full,
                                                      const float* __restrict__ wl1,
                                                      const float* __restrict__ wT,
                                                      const float* __restrict__ wl2,
                                                      const float* __restrict__ image,
                                                      float* __restrict__ out,
                                                      int k, int sparse) {
    __shared__ union __align__(16) {
        float spk[CPC][10][58];           // 9.28 KB (partial)
        float sim[NIN];                   // 16 KB  (conv1)
        double fin[256];                  // 2 KB   (finish)
        struct { int wcnt[4]; int base; } red;  // (reduce list-build)
        float tile[64][65];               // 16.64 KB (transpose strip)
    } sm;
    int nb = blockIdx.x, tid = threadIdx.x;
    int wid = tid >> 6, lane = tid & 63;

    if (nb < R_PART) {
        // ---- conv2 partial, step s=k in [2,17]: reads sp_c1(k-1) ----
        if (k < 2 || k > 17) return;
        int kc = nb & 15;
        int tmp = nb >> 4;             // 0..51
        int cotg = tmp & 3;
        int yt = tmp >> 2;             // 0..12
        int c0 = kc * CPC, y0 = yt * 4;
        const float* __restrict__ sp = g_sp_c1[(k + 1) & 1];
        for (int e = tid; e < CPC * 10 * 58; e += 256) {
            int c = e / 580, rem = e - c * 580;
            int r = rem / 58, x = rem - r * 58;
            sm.spk[c][r][x] = sp[(c0 + c) * (D1 * D1) + (y0 + r) * D1 + x];
        }
        __syncthreads();
        int cot = __builtin_amdgcn_readfirstlane(cotg * 4 + wid);
        int co0 = cot * 8;
        float acc[8][4] = {};
        bool act = lane < D2;
        float* __restrict__ pb = g_part[k & 1];
#pragma unroll 1
        for (int c = 0; c < CPC; ++c) {
#pragma unroll
            for (int ky = 0; ky < K2; ++ky) {
                // hoist spike regs out of the cl loop (28 ds_reads / 224 FMA)
                float v[4][7];
                if (act) {
#pragma unroll
                    for (int o = 0; o < 4; ++o)
#pragma unroll
                        for (int kx = 0; kx < 7; ++kx)
                            v[o][kx] = sm.spk[c][o + ky][lane + kx];
                }
                const float* __restrict__ wrow =
                    g_w2r + ((size_t)(kc * 16 + cot) * 28 + (c * 7 + ky)) * 64;
#pragma unroll
                for (int cl = 0; cl < 8; ++cl) {
                    float wv[7];   // 7 live scalar weights at a time
#pragma unroll
                    for (int kx = 0; kx < 7; ++kx) wv[kx] = wrow[cl * 8 + kx];
                    if (act) {
#pragma unroll
                        for (int o = 0; o < 4; ++o)
#pragma unroll
                            for (int kx = 0; kx < 7; ++kx)
                                acc[cl][o] = fmaf(v[o][kx], wv[kx], acc[cl][o]);
                    }
                }
            }
        }
        if (act) {
#pragma unroll
            for (int cl = 0; cl < 8; ++cl)
#pragma unroll
                for (int o = 0; o < 4; ++o)
                    pb[(size_t)kc * N2 + (co0 + cl) * (D2 * D2) + (y0 + o) * D2 + lane] =
                        acc[cl][o];
        }
    } else if (nb < B_FIN0) {
        // ---- conv1, step s=k in [1,16]: reads s_in(k) ----
        if (k < 1 || k > 16) return;
        int co = nb - B_C1S;
        const float4* __restrict__ s4 = (const float4*)g_s_in[k & 1];
        float4* d4 = (float4*)sm.sim;
        for (int j = tid; j < NIN / 4; j += 256) d4[j] = s4[j];
        __syncthreads();
        float w[49];
#pragma unroll
        for (int kk = 0; kk < 49; ++kk) w[kk] = w1[co * 49 + kk];
        float* __restrict__ spb = g_sp_c1[k & 1];
        for (int idx = tid; idx < D1 * D1; idx += 256) {
            int y = idx / D1, x = idx - y * D1;
            float a = 0.f;
#pragma unroll
            for (int ky = 0; ky < K1; ++ky)
#pragma unroll
                for (int kx = 0; kx < K1; ++kx)
                    a = fmaf(sm.sim[(y + ky) * DIM_IN + x + kx], w[ky * K1 + kx], a);
            int o = co * (D1 * D1) + idx;
            float mp = g_mp_c1[o] + a;
            float f = (mp >= THRES) ? 1.f : 0.f;
            g_mp_c1[o] = (mp - THRES * f) * ((f > 0.f) ? 1.f : DECAY);
            spb[o] = f;
        }
    } else if (nb < B_INPUT) {
        // ---- linear1 finish, step s=k-2 in [3,18]: reads dotp(s) ----
        if (k < 5 || k > 20) return;
        int s = k - 2;
        int fb = nb - B_FIN0;              // 0..7
        int hl = tid & 63, wch = tid >> 6;
        int h = fb * 64 + hl;
        float tot;
        if (sparse) {
            int p = s & 1;
            double sum = 0.0;
            int b0 = wch * (R_GATH / 4);   // 96 blocks per chunk
            for (int b = b0; b < b0 + R_GATH / 4; ++b) sum += g_dotp[p][b][h];
            sm.fin[wch * 64 + hl] = sum;
            __syncthreads();
            if (wch != 0) return;
            tot = (float)((sm.fin[hl] + sm.fin[64 + hl]) +
                          (sm.fin[128 + hl] + sm.fin[192 + hl]));
        } else {
            if (wch != 0) return;
            tot = g_dot[s & 1][h];
        }
        float mp = g_mp_l1[h] * DECAY + tot;
        float f = (mp >= THRES) ? 1.f : 0.f;
        g_mp_l1[h] = mp - THRES * f;
        g_sp_l1[s & 1][h] = f;
    } else if (nb == B_INPUT) {
        // ---- input integrate/fire, step s=k+1 in [2,16] ----
        if (k < 1 || k > 15) return;
        int s = k + 1;
        float* __restrict__ sb = g_s_in[s & 1];
        for (int j = tid; j < NIN; j += 256) {
            float mp = g_mp_in[j] + image[j];
            float f = (mp >= THRES) ? 1.f : 0.f;
            sb[j] = f;
            g_mp_in[j] = mp - THRES * f;   // SnnInput: no decay
        }
    } else if (nb == B_LIN2) {
        // ---- linear2, step s=k-2 in [4,19]: reads sp_l1(s-1) ----
        if (k < 6 || k > 21) return;
        int s = k - 2;
        const float* __restrict__ sl = g_sp_l1[(s - 1) & 1];
        for (int o = wid; o < NOUT; o += 4) {
            float a = 0.f;
#pragma unroll
            for (int kk = lane; kk < NHID; kk += 64)
                a = fmaf(wl2[o * NHID + kk], sl[kk], a);
            for (int off = 32; off; off >>= 1) a += __shfl_down(a, off, 64);
            if (lane == 0) {
                float mp = g_mp_l2[o] * DECAY + a;
                float f = (mp >= THRES) ? 1.f : 0.f;
                g_mp_l2[o] = mp - THRES * f;
                out[(s + 1) * NOUT + o] = f;
            }
        }
    } else if (nb == B_MISC) {
        // ---- misc: zero nnz[k&3] for reduce(k) (runs in D_{k+1}) ----
        if (k < 2 || k > 17) return;
        if (tid == 0) g_nnz[k & 3] = 0;
    } else if (nb < B_RED0) {
        // ---- linear1 gather, step s=k-1 in [3,18]: reads list(s-1) ----
        // 384 deeper blocks: ~2 co-resident batches complete within the
        // partial phase's VALU shadow.
        if (!sparse || k < 4 || k > 19) return;
        int s = k - 1;
        int gb = nb - B_GATH0;
        int ps = (s - 1) & 3;
        int nnz = g_nnz[ps];
        const int* __restrict__ list = g_list[ps];
        const float2* __restrict__ wT2 = (const float2*)wT;
        int h = tid;
        double ax[8] = {}, ay[8] = {};
        int i = gb;
        for (; i + 7 * R_GATH < nnz; i += 8 * R_GATH) {
            int j[8];
#pragma unroll
            for (int u = 0; u < 8; ++u) j[u] = list[i + u * R_GATH];
#pragma unroll
            for (int u = 0; u < 8; ++u) {
                float2 w = wT2[(size_t)j[u] * 256 + h];
                ax[u] += w.x; ay[u] += w.y;
            }
        }
        for (; i < nnz; i += R_GATH) {
            float2 w = wT2[(size_t)list[i] * 256 + h];
            ax[0] += w.x; ay[0] += w.y;
        }
        g_dotp[s & 1][gb][2 * h] =
            ((ax[0] + ax[1]) + (ax[2] + ax[3])) + ((ax[4] + ax[5]) + (ax[6] + ax[7]));
        g_dotp[s & 1][gb][2 * h + 1] =
            ((ay[0] + ay[1]) + (ay[2] + ay[3])) + ((ay[4] + ay[5]) + (ay[6] + ay[7]));
    } else if (nb < NBS) {
        // ---- conv2 reduce, step s=k-1 in [2,17]: block-aggregated list ----
        if (k < 3 || k > 18) return;
        int s = k - 1;
        int i = (nb - B_RED0) * 256 + tid;
        const float* __restrict__ pb = g_part[s & 1];
        float sum = 0.f;
#pragma unroll
        for (int kk = 0; kk < KC; ++kk) sum += pb[(size_t)kk * N2 + i];
        float mp = g_mp_c2[i] + sum;
        float f = (mp >= THRES) ? 1.f : 0.f;
        g_mp_c2[i] = (mp - THRES * f) * ((f > 0.f) ? 1.f : DECAY);
        if (!sparse) g_sp_c2[i] = f;
        bool spike = f > 0.f;
        unsigned long long m = __ballot(spike);
        int lpre = __popcll(m & ((1ull << lane) - 1));
        if (lane == 0) sm.red.wcnt[wid] = __popcll(m);
        __syncthreads();
        int w0 = sm.red.wcnt[0], w1c = sm.red.wcnt[1],
            w2c = sm.red.wcnt[2], w3c = sm.red.wcnt[3];
        int total = w0 + w1c + w2c + w3c;
        if (tid == 0 && total > 0)
            sm.red.base = atomicAdd(&g_nnz[s & 3], total);
        __syncthreads();
        if (spike) {
            int woff = (wid > 0 ? w0 : 0) + (wid > 1 ? w1c : 0) + (wid > 2 ? w2c : 0);
            g_list[s & 3][sm.red.base + woff + lpre] = i;
        }
    } else if (nb < B_RSH0) {
        // ---- transpose strip (k<=3, appended): w_l1 -> wT, 64-col strip ----
        if (!sparse || k > 3) return;
        int sg = (nb - B_TR0) + (k - 1) * NT;
        if (sg >= NFLAT / 64) return;
        int bx = sg * 64;
        int tx = tid & 63, ty = tid >> 6;
        float* __restrict__ wTm = (float*)wT;
#pragma unroll 1
        for (int rt = 0; rt < NHID / 64; ++rt) {
            int by = rt * 64;
#pragma unroll
            for (int kk = 0; kk < 16; ++kk)
                sm.tile[ty + 4 * kk][tx] =
                    wl1[(size_t)(by + ty + 4 * kk) * NFLAT + bx + tx];
            __syncthreads();
#pragma unroll
            for (int kk = 0; kk < 16; ++kk)
                wTm[(size_t)(bx + ty + 4 * kk) * NHID + by + tx] =
                    sm.tile[tx][ty + 4 * kk];
            __syncthreads();
        }
    } else {
        // ---- reshuffle w_c2 -> g_w2r (k==1 only, appended, 64 blocks) ----
        // layout: [(kc*16+cot8)][c*7+ky][cl*8+kx], cl in [0,8), kx pad 8
        if (k != 1) return;
        int rb = nb - B_RSH0;              // 0..63
        for (int idx = rb * 256 + tid; idx < C2 * C1 * 49; idx += 64 * 256) {
            int co = idx / (C1 * 49);
            int rem = idx - co * (C1 * 49);
            int ci = rem / 49;
            int kk2 = rem - ci * 49;
            int ky = kk2 / 7, kx = kk2 - ky * 7;
            int kc = ci >> 2, c = ci & 3;
            int cot = co >> 3, cl = co & 7;
            g_w2r[((size_t)(kc * 16 + cot) * 28 + (c * 7 + ky)) * 64 + cl * 8 + kx] =
                w2full[idx];
        }
    }
}

// Dense fallback (ws too small for wT): writes g_dot[slot]; finish applies it.
__global__ void __launch_bounds__(256) linear1_dense(const float* __restrict__ wl1,
                                                     int slot) {
    int row = blockIdx.x;
    const float4* __restrict__ w4 = (const float4*)(wl1 + (size_t)row * NFLAT);
    const float4* __restrict__ s4 = (const float4*)g_sp_c2;
    float acc = 0.f;
    for (int j = threadIdx.x; j < NFLAT / 4; j += 256) {
        float4 w = w4[j];
        float4 s = s4[j];
        acc += w.x * s.x + w.y * s.y + w.z * s.z + w.w * s.w;
    }
    __shared__ float red[256];
    red[threadIdx.x] = acc;
    __syncthreads();
    for (int off = 128; off >= 1; off >>= 1) {
        if (threadIdx.x < off) red[threadIdx.x] += red[threadIdx.x + off];
        __syncthreads();
    }
    if (threadIdx.x == 0) g_dot[slot][row] = red[0];
}

extern "C" void kernel_launch(void* const* d_in, const int* in_sizes, int n_in,
                              void* d_out, int out_size, void* d_ws, size_t ws_size,
                              hipStream_t stream) {
    const float* image = (const float*)d_in[0];
    const float* w_c1 = (const float*)d_in[1];
    const float* w_c2 = (const float*)d_in[2];
    const float* w_l1 = (const float*)d_in[3];
    const float* w_l2 = (const float*)d_in[4];
    float* out = (float*)d_out;

    float* wT = (float*)d_ws;
    bool sparse = ws_size >= (size_t)NFLAT * NHID * sizeof(float);

    init_kernel<<<512, 256, 0, stream>>>(image, out);

    // Pipeline: D_k = partial(k)|conv1(k)|finish(k-2)|input(k+1)|linear2(k-2)
    //                 |misc|gather(k-1)|reduce(k-1) [+transpose k<=3].
    for (int k = 1; k <= 21; ++k) {
        int grid = (k <= 3) ? NBS_T : NBS;
        step_kernel<<<grid, 256, 0, stream>>>(w_c1, w_c2, w_l1, wT, w_l2, image,
                                              out, k, sparse ? 1 : 0);
        if (!sparse && k >= 3 && k <= 18)
            linear1_dense<<<NHID, 256, 0, stream>>>(w_l1, k & 1);
    }
}